// Round 1
// baseline (202.010 us; speedup 1.0000x reference)
//
#include <hip/hip_runtime.h>
#include <math.h>

#define CIN    64
#define OUTC   64
#define BOT    16
#define KK     9
#define HH     48
#define WW     48
#define LPIX   (HH*WW)
#define WSZ    9216
#define PSZ    1024
#define PREDCH 10304
#define GRPSZ  2576
#define BATCH  2
#define NPX    9           // 3 rows x 3 cols of pixels per block (1 px per wave)
#define PXS2   1172        // px-stride (ushorts): 64*18 + 20 pad (conflict-free)
#define DBS    65

typedef __attribute__((ext_vector_type(8))) short short8v;
typedef __attribute__((ext_vector_type(4))) float float4v;

__device__ inline unsigned short f2bf(float f){
    unsigned u = __float_as_uint(f);
    return (unsigned short)((u + 0x7FFFu + ((u>>16)&1u)) >> 16);   // RNE
}

__global__ __launch_bounds__(256) void cvt_wp(const float* __restrict__ Wp,
                                              unsigned short* __restrict__ Wb) {
    const int n = PREDCH * 16;
    for (int i = blockIdx.x * 256 + threadIdx.x; i < n; i += gridDim.x * 256)
        Wb[i] = f2bf(Wp[i]);
}

// Block = 9 px (3x3), grid 512 (2/CU!), 576 threads (9 waves, 1 px per wave).
// vs dppc7: NPX 18->9 halves LDS (54.7 KB) so 2 blocks co-reside per CU
// (18 waves/CU = 2x occupancy). Per-px pred cost unchanged (single nt=0
// MFMA column-set now covers all 9 px). Double-buffered P_t retained.
__global__ __launch_bounds__(576, 5) void dppc8(
    const float* __restrict__ x,
    const unsigned short* __restrict__ Wb,
    const float* __restrict__ bp,
    float* __restrict__ out)
{
    __shared__ float          xt[64 * 5 * 8];       // 10240 B  [c][r5][c8]
    __shared__ unsigned short S[2][NPX * PXS2];     // 42192 B  P_t dbuf; S[0] also stages Q
    __shared__ float          dynb[NPX * DBS];      //  2340 B

    const int tid  = threadIdx.x;
    const int wave = tid >> 6;
    const int lane = tid & 63;
    const int quad = lane >> 4;
    const int lrow = lane & 15;

    const int bi = blockIdx.x;
    const int b  = bi >> 8;          // 256 px-blocks per batch image
    const int r  = bi & 255;
    const int h0 = (r >> 4) * 3;     // 16x16 regions of 3x3 px
    const int w0 = (r & 15) * 3;

    // ---- xt load (5x5 window needed; 8-col stride kept for banking) ----
    const float* xb = x + (size_t)b * CIN * LPIX;
    for (int i = tid; i < 64 * 5 * 8; i += 576) {
        const int c  = i / 40;
        const int rm = i - c * 40;
        const int hi = h0 - 1 + (rm >> 3);
        const int wi = w0 - 1 + (rm & 7);
        float v = 0.0f;
        if (hi >= 0 && hi < HH && wi >= 0 && wi < WW)
            v = xb[c * LPIX + hi * WW + wi];
        xt[i] = v;
    }
    __syncthreads();

    // ---- pred B-frags from center x (t-independent); single nt (NPX=9<=16) ----
    short8v Bf[4];
    #pragma unroll
    for (int g = 0; g < 4; ++g) {
        const int px = lrow;
        short8v f = (short8v)0;
        if (quad < 2 && px < NPX) {
            const int pr = px / 3, pc = px - 3 * (px / 3);
            #pragma unroll
            for (int j = 0; j < 8; ++j)
                f[j] = (short)f2bf(xt[((g * 16 + quad * 8 + j) * 5 + pr + 1) * 8 + pc + 1]);
        }
        if (quad == 2 && px < NPX) f[0] = (short)0x3F80;   // bf16(1.0) bias slot
        Bf[g] = f;
    }

    // ---- Q + dyn_b phase (group 3), Q -> S[0] as [px][o*18+d] ----
    for (int u = wave; u < 68; u += 9) {
        const int ch0  = WSZ + u * 16;
        const int mych = ch0 + lrow;
        short8v a = (short8v)0;
        if (quad < 2)       a = *(const short8v*)(Wb + (size_t)mych * 16 + quad * 8);
        else if (quad == 2) a[0] = (short)f2bf(bp[mych]);
        float4v Dv = {0.f, 0.f, 0.f, 0.f};
        Dv = __builtin_amdgcn_mfma_f32_16x16x32_bf16(a, Bf[3], Dv, 0, 0, 0);
        const int px = lrow;
        if (px < NPX) {
            #pragma unroll
            for (int rr = 0; rr < 4; ++rr) {
                const int ch = ch0 + quad * 4 + rr;
                if (ch < WSZ + PSZ) {
                    const int i = ch - WSZ;
                    S[0][px * PXS2 + (i >> 4) * 18 + (i & 15)] = f2bf(Dv[rr]);
                } else {
                    dynb[px * DBS + (ch - WSZ - PSZ)] = Dv[rr];
                }
            }
        }
    }
    __syncthreads();

    // ---- cache Q B-frags in registers: this wave's pixel ----
    const int px0 = wave;                       // 0..8, exactly 1 px per wave
    const int pr0 = px0 / 3, pc0 = px0 - 3 * (px0 / 3);
    short8v Bq[4];
    #pragma unroll
    for (int Nt = 0; Nt < 4; ++Nt) {
        short8v f = (short8v)0;
        if (quad < 2)
            f = *(const short8v*)&S[0][px0 * PXS2 + (Nt * 16 + lrow) * 18 + quad * 8];
        Bq[Nt] = f;
    }
    __syncthreads();   // all waves done reading S[0] before pred(0) overwrites it

    float acc[4] = {};

    // ---- pred slice for tap t into buf (STATIC Bf indices via literal PASS) ----
    #define PASS(GG)                                                                  \
        { short8v am = (myg == (GG)) ? a : (short8v)0;                                \
          Dv = __builtin_amdgcn_mfma_f32_16x16x32_bf16(am, Bf[GG], Dv, 0, 0, 0); }

    #define PRED_SLICE(T, BUF)                                                        \
    for (int u = wave; u < 64; u += 9) {                                              \
        const int d  = u >> 2;                                                        \
        const int c0 = (u & 3) * 16;                                                  \
        const int ch0  = d * 576 + c0 * 9 + (T);                                      \
        const int mych = ch0 + 9 * lrow;                                              \
        short8v a = (short8v)0;                                                       \
        if (quad < 2)       a = *(const short8v*)(Wb + (size_t)mych * 16 + quad * 8); \
        else if (quad == 2) a[0] = (short)f2bf(bp[mych]);                             \
        const int g0  = ch0 / GRPSZ;                                                  \
        const int g1  = (ch0 + 135) / GRPSZ;                                          \
        const int myg = mych / GRPSZ;                                                 \
        float4v Dv = {0.f, 0.f, 0.f, 0.f};                                            \
        if (g0 == 0)      { PASS(0) if (g1 == 1) PASS(1) }                            \
        else if (g0 == 1) { PASS(1) if (g1 == 2) PASS(2) }                            \
        else if (g0 == 2) { PASS(2) if (g1 == 3) PASS(3) }                            \
        else              { PASS(3) }                                                 \
        const int px = lrow;                                                          \
        if (px < NPX) {                                                               \
            _Pragma("unroll")                                                         \
            for (int rr = 0; rr < 4; ++rr)                                            \
                S[BUF][px * PXS2 + (c0 + quad * 4 + rr) * 18 + d] = f2bf(Dv[rr]);     \
        }                                                                             \
    }

    PRED_SLICE(0, 0)
    __syncthreads();

    for (int t = 0; t < KK; ++t) {
        const int buf = t & 1;
        if (t < 8) { PRED_SLICE(t + 1, (t + 1) & 1) }

        // ---- Y = P_t^T Q for this wave's pixel ----
        const int tr = t / 3, tc = t - 3 * (t / 3);

        short8v Ap[4];
        #pragma unroll
        for (int Mt = 0; Mt < 4; ++Mt) {
            short8v f = (short8v)0;
            if (quad < 2)
                f = *(const short8v*)&S[buf][px0 * PXS2 + (Mt * 16 + lrow) * 18 + quad * 8];
            Ap[Mt] = f;
        }
        float pv[4][4];
        #pragma unroll
        for (int Mt = 0; Mt < 4; ++Mt)
            #pragma unroll
            for (int rr = 0; rr < 4; ++rr) {
                const int c = Mt * 16 + quad * 4 + rr;
                pv[Mt][rr] = xt[(c * 5 + pr0 + tr) * 8 + pc0 + tc];
            }

        #pragma unroll
        for (int Nt = 0; Nt < 4; ++Nt) {
            float nacc = 0.f, dpacc = 0.f;
            #pragma unroll
            for (int Mt = 0; Mt < 4; ++Mt) {
                float4v Dv = {0.f, 0.f, 0.f, 0.f};
                Dv = __builtin_amdgcn_mfma_f32_16x16x32_bf16(Ap[Mt], Bq[Nt], Dv, 0, 0, 0);
                #pragma unroll
                for (int rr = 0; rr < 4; ++rr) {
                    nacc  += Dv[rr] * Dv[rr];
                    dpacc += pv[Mt][rr] * Dv[rr];
                }
            }
            nacc  += __shfl_xor(nacc, 16);  nacc  += __shfl_xor(nacc, 32);
            dpacc += __shfl_xor(dpacc, 16); dpacc += __shfl_xor(dpacc, 32);
            acc[Nt] += dpacc / fmaxf(sqrtf(fmaxf(nacc, 0.f)), 1e-12f);
        }
        __syncthreads();
    }

    // ---- write out ----
    if (quad == 0) {
        const int l = (h0 + pr0) * WW + (w0 + pc0);
        #pragma unroll
        for (int Nt = 0; Nt < 4; ++Nt) {
            const int o = Nt * 16 + lrow;
            out[((size_t)b * OUTC + o) * LPIX + l] = acc[Nt] + dynb[px0 * DBS + o];
        }
    }
}

extern "C" void kernel_launch(void* const* d_in, const int* in_sizes, int n_in,
                              void* d_out, int out_size, void* d_ws, size_t ws_size,
                              hipStream_t stream) {
    const float* x  = (const float*)d_in[0];
    const float* Wp = (const float*)d_in[1];
    const float* bp = (const float*)d_in[2];
    float* out = (float*)d_out;
    unsigned short* Wb = (unsigned short*)d_ws;   // PREDCH*16 bf16 = 330 KB
    (void)in_sizes; (void)n_in; (void)out_size; (void)ws_size;

    hipLaunchKernelGGL(cvt_wp, dim3(160), dim3(256), 0, stream, Wp, Wb);
    hipLaunchKernelGGL(dppc8, dim3(BATCH * 256), dim3(576), 0, stream, x, Wb, bp, out);
}

// Round 2
// 178.800 us; speedup vs baseline: 1.1298x; 1.1298x over previous
//
#include <hip/hip_runtime.h>
#include <math.h>

#define CIN    64
#define OUTC   64
#define BOT    16
#define KK     9
#define HH     48
#define WW     48
#define LPIX   (HH*WW)
#define WSZ    9216
#define PSZ    1024
#define PREDCH 10304
#define GRPSZ  2576
#define BATCH  2
#define NPX    9           // 3 rows x 3 cols of pixels per block (1 px per wave)
#define PXS2   1172        // px-stride (ushorts): 64*18 + 20 pad (conflict-free)
#define DBS    65

typedef __attribute__((ext_vector_type(8))) short short8v;
typedef __attribute__((ext_vector_type(4))) float float4v;

__device__ inline unsigned short f2bf(float f){
    unsigned u = __float_as_uint(f);
    return (unsigned short)((u + 0x7FFFu + ((u>>16)&1u)) >> 16);   // RNE
}

__global__ __launch_bounds__(256) void cvt_wp(const float* __restrict__ Wp,
                                              unsigned short* __restrict__ Wb) {
    const int n = PREDCH * 16;
    for (int i = blockIdx.x * 256 + threadIdx.x; i < n; i += gridDim.x * 256)
        Wb[i] = f2bf(Wp[i]);
}

// Block = 9 px (3x3), grid 512 (2/CU), 576 threads (9 waves, 1 px per wave).
// vs dppc8 (R1): launch_bounds min-waves arg REMOVED back to 3 — the (576,5)
// hint drove the allocator to 48 VGPRs + heavy scratch spills (WRITE_SIZE
// 22.8 MB), which both stalled waves and blocked the 2nd workgroup from
// co-residing (scratch-limited occupancy). With (576,3) the compiler should
// land ~64-84 VGPRs (no spill); two 9-wave blocks then fit per CU
// (LDS 2x54.7KB <= 160KB, worst-SIMD 6 waves x <=85 VGPR <= 512).
__global__ __launch_bounds__(576, 3) void dppc9(
    const float* __restrict__ x,
    const unsigned short* __restrict__ Wb,
    const float* __restrict__ bp,
    float* __restrict__ out)
{
    __shared__ float          xt[64 * 5 * 8];       // 10240 B  [c][r5][c8]
    __shared__ unsigned short S[2][NPX * PXS2];     // 42192 B  P_t dbuf; S[0] also stages Q
    __shared__ float          dynb[NPX * DBS];      //  2340 B

    const int tid  = threadIdx.x;
    const int wave = tid >> 6;
    const int lane = tid & 63;
    const int quad = lane >> 4;
    const int lrow = lane & 15;

    const int bi = blockIdx.x;
    const int b  = bi >> 8;          // 256 px-blocks per batch image
    const int r  = bi & 255;
    const int h0 = (r >> 4) * 3;     // 16x16 regions of 3x3 px
    const int w0 = (r & 15) * 3;

    // ---- xt load (5x5 window needed; 8-col stride kept for banking) ----
    const float* xb = x + (size_t)b * CIN * LPIX;
    for (int i = tid; i < 64 * 5 * 8; i += 576) {
        const int c  = i / 40;
        const int rm = i - c * 40;
        const int hi = h0 - 1 + (rm >> 3);
        const int wi = w0 - 1 + (rm & 8 - 1);
        float v = 0.0f;
        if (hi >= 0 && hi < HH && wi >= 0 && wi < WW)
            v = xb[c * LPIX + hi * WW + wi];
        xt[i] = v;
    }
    __syncthreads();

    // ---- pred B-frags from center x (t-independent); single nt (NPX=9<=16) ----
    short8v Bf[4];
    #pragma unroll
    for (int g = 0; g < 4; ++g) {
        const int px = lrow;
        short8v f = (short8v)0;
        if (quad < 2 && px < NPX) {
            const int pr = px / 3, pc = px - 3 * (px / 3);
            #pragma unroll
            for (int j = 0; j < 8; ++j)
                f[j] = (short)f2bf(xt[((g * 16 + quad * 8 + j) * 5 + pr + 1) * 8 + pc + 1]);
        }
        if (quad == 2 && px < NPX) f[0] = (short)0x3F80;   // bf16(1.0) bias slot
        Bf[g] = f;
    }

    // ---- Q + dyn_b phase (group 3), Q -> S[0] as [px][o*18+d] ----
    for (int u = wave; u < 68; u += 9) {
        const int ch0  = WSZ + u * 16;
        const int mych = ch0 + lrow;
        short8v a = (short8v)0;
        if (quad < 2)       a = *(const short8v*)(Wb + (size_t)mych * 16 + quad * 8);
        else if (quad == 2) a[0] = (short)f2bf(bp[mych]);
        float4v Dv = {0.f, 0.f, 0.f, 0.f};
        Dv = __builtin_amdgcn_mfma_f32_16x16x32_bf16(a, Bf[3], Dv, 0, 0, 0);
        const int px = lrow;
        if (px < NPX) {
            #pragma unroll
            for (int rr = 0; rr < 4; ++rr) {
                const int ch = ch0 + quad * 4 + rr;
                if (ch < WSZ + PSZ) {
                    const int i = ch - WSZ;
                    S[0][px * PXS2 + (i >> 4) * 18 + (i & 15)] = f2bf(Dv[rr]);
                } else {
                    dynb[px * DBS + (ch - WSZ - PSZ)] = Dv[rr];
                }
            }
        }
    }
    __syncthreads();

    // ---- cache Q B-frags in registers: this wave's pixel ----
    const int px0 = wave;                       // 0..8, exactly 1 px per wave
    const int pr0 = px0 / 3, pc0 = px0 - 3 * (px0 / 3);
    short8v Bq[4];
    #pragma unroll
    for (int Nt = 0; Nt < 4; ++Nt) {
        short8v f = (short8v)0;
        if (quad < 2)
            f = *(const short8v*)&S[0][px0 * PXS2 + (Nt * 16 + lrow) * 18 + quad * 8];
        Bq[Nt] = f;
    }
    __syncthreads();   // all waves done reading S[0] before pred(0) overwrites it

    float acc[4] = {};

    // ---- pred slice for tap t into buf (STATIC Bf indices via literal PASS) ----
    #define PASS(GG)                                                                  \
        { short8v am = (myg == (GG)) ? a : (short8v)0;                                \
          Dv = __builtin_amdgcn_mfma_f32_16x16x32_bf16(am, Bf[GG], Dv, 0, 0, 0); }

    #define PRED_SLICE(T, BUF)                                                        \
    for (int u = wave; u < 64; u += 9) {                                              \
        const int d  = u >> 2;                                                        \
        const int c0 = (u & 3) * 16;                                                  \
        const int ch0  = d * 576 + c0 * 9 + (T);                                      \
        const int mych = ch0 + 9 * lrow;                                              \
        short8v a = (short8v)0;                                                       \
        if (quad < 2)       a = *(const short8v*)(Wb + (size_t)mych * 16 + quad * 8); \
        else if (quad == 2) a[0] = (short)f2bf(bp[mych]);                             \
        const int g0  = ch0 / GRPSZ;                                                  \
        const int g1  = (ch0 + 135) / GRPSZ;                                          \
        const int myg = mych / GRPSZ;                                                 \
        float4v Dv = {0.f, 0.f, 0.f, 0.f};                                            \
        if (g0 == 0)      { PASS(0) if (g1 == 1) PASS(1) }                            \
        else if (g0 == 1) { PASS(1) if (g1 == 2) PASS(2) }                            \
        else if (g0 == 2) { PASS(2) if (g1 == 3) PASS(3) }                            \
        else              { PASS(3) }                                                 \
        const int px = lrow;                                                          \
        if (px < NPX) {                                                               \
            _Pragma("unroll")                                                         \
            for (int rr = 0; rr < 4; ++rr)                                            \
                S[BUF][px * PXS2 + (c0 + quad * 4 + rr) * 18 + d] = f2bf(Dv[rr]);     \
        }                                                                             \
    }

    PRED_SLICE(0, 0)
    __syncthreads();

    for (int t = 0; t < KK; ++t) {
        const int buf = t & 1;
        if (t < 8) { PRED_SLICE(t + 1, (t + 1) & 1) }

        // ---- Y = P_t^T Q for this wave's pixel ----
        const int tr = t / 3, tc = t - 3 * (t / 3);

        short8v Ap[4];
        #pragma unroll
        for (int Mt = 0; Mt < 4; ++Mt) {
            short8v f = (short8v)0;
            if (quad < 2)
                f = *(const short8v*)&S[buf][px0 * PXS2 + (Mt * 16 + lrow) * 18 + quad * 8];
            Ap[Mt] = f;
        }
        float pv[4][4];
        #pragma unroll
        for (int Mt = 0; Mt < 4; ++Mt)
            #pragma unroll
            for (int rr = 0; rr < 4; ++rr) {
                const int c = Mt * 16 + quad * 4 + rr;
                pv[Mt][rr] = xt[(c * 5 + pr0 + tr) * 8 + pc0 + tc];
            }

        #pragma unroll
        for (int Nt = 0; Nt < 4; ++Nt) {
            float nacc = 0.f, dpacc = 0.f;
            #pragma unroll
            for (int Mt = 0; Mt < 4; ++Mt) {
                float4v Dv = {0.f, 0.f, 0.f, 0.f};
                Dv = __builtin_amdgcn_mfma_f32_16x16x32_bf16(Ap[Mt], Bq[Nt], Dv, 0, 0, 0);
                #pragma unroll
                for (int rr = 0; rr < 4; ++rr) {
                    nacc  += Dv[rr] * Dv[rr];
                    dpacc += pv[Mt][rr] * Dv[rr];
                }
            }
            nacc  += __shfl_xor(nacc, 16);  nacc  += __shfl_xor(nacc, 32);
            dpacc += __shfl_xor(dpacc, 16); dpacc += __shfl_xor(dpacc, 32);
            acc[Nt] += dpacc / fmaxf(sqrtf(fmaxf(nacc, 0.f)), 1e-12f);
        }
        __syncthreads();
    }

    // ---- write out ----
    if (quad == 0) {
        const int l = (h0 + pr0) * WW + (w0 + pc0);
        #pragma unroll
        for (int Nt = 0; Nt < 4; ++Nt) {
            const int o = Nt * 16 + lrow;
            out[((size_t)b * OUTC + o) * LPIX + l] = acc[Nt] + dynb[px0 * DBS + o];
        }
    }
}

extern "C" void kernel_launch(void* const* d_in, const int* in_sizes, int n_in,
                              void* d_out, int out_size, void* d_ws, size_t ws_size,
                              hipStream_t stream) {
    const float* x  = (const float*)d_in[0];
    const float* Wp = (const float*)d_in[1];
    const float* bp = (const float*)d_in[2];
    float* out = (float*)d_out;
    unsigned short* Wb = (unsigned short*)d_ws;   // PREDCH*16 bf16 = 330 KB
    (void)in_sizes; (void)n_in; (void)out_size; (void)ws_size;

    hipLaunchKernelGGL(cvt_wp, dim3(160), dim3(256), 0, stream, Wp, Wb);
    hipLaunchKernelGGL(dppc9, dim3(BATCH * 256), dim3(576), 0, stream, x, Wb, bp, out);
}

// Round 3
// 136.230 us; speedup vs baseline: 1.4829x; 1.3125x over previous
//
#include <hip/hip_runtime.h>
#include <math.h>

#define CIN    64
#define OUTC   64
#define BOT    16
#define KK     9
#define HH     48
#define WW     48
#define LPIX   (HH*WW)
#define WSZ    9216
#define PSZ    1024
#define PREDCH 10304
#define GRPSZ  2576
#define BATCH  2
#define NPX    18          // 3 rows x 6 cols of pixels per block
#define PXS2   1172        // px-stride (ushorts): 64*18 + 20 pad (conflict-free)
#define QS2    1160        // Q px-stride (ushorts): 64*18 + 8 pad
#define DBS    65

typedef __attribute__((ext_vector_type(8))) short short8v;
typedef __attribute__((ext_vector_type(4))) float float4v;

__device__ inline unsigned short f2bf(float f){
    unsigned u = __float_as_uint(f);
    return (unsigned short)((u + 0x7FFFu + ((u>>16)&1u)) >> 16);   // RNE
}

__global__ __launch_bounds__(256) void cvt_wp(const float* __restrict__ Wp,
                                              unsigned short* __restrict__ Wb) {
    const int n = PREDCH * 16;
    for (int i = blockIdx.x * 256 + threadIdx.x; i < n; i += gridDim.x * 256)
        Wb[i] = f2bf(Wp[i]);
}

// Block = 18 px (3x6), grid 256 (1/CU), 1024 threads (16 waves).
// vs dppc7 (9 waves): 2-WG co-residency never materialized (R1/R2), and
// NPX=9 doubled per-px pred cost (pred u-loop is per-BLOCK fixed).  So get
// parallelism INSIDE the block: 16 waves = 4/SIMD (50% occ) with the same
// NPX=18 pred amortization.  Y-phase becomes 72 (px,Nt) tasks over 16
// waves; Q lives in its own LDS region (read per task) instead of the
// S[0]-staging trick, which also deletes two barriers.  LDS 141 KB, 1 WG/CU
// by construction.  launch_bounds(1024) alone caps VGPR at 128 (no R1-style
// min-waves misfire).
__global__ __launch_bounds__(1024) void dppc10(
    const float* __restrict__ x,
    const unsigned short* __restrict__ Wb,
    const float* __restrict__ bp,
    float* __restrict__ out)
{
    __shared__ float          xt[64 * 5 * 8];       // 10240 B  [c][r5][c8]
    __shared__ unsigned short S[2][NPX * PXS2];     // 84384 B  P_t dbuf
    __shared__ unsigned short Qs[NPX * QS2];        // 41760 B  Q [px][o*18+d]
    __shared__ float          dynb[NPX * DBS];      //  4680 B

    const int tid  = threadIdx.x;
    const int wave = tid >> 6;
    const int lane = tid & 63;
    const int quad = lane >> 4;
    const int lrow = lane & 15;

    const int bi = blockIdx.x;
    const int b  = bi >> 7;
    const int r  = bi & 127;
    const int h0 = (r >> 3) * 3;
    const int w0 = (r & 7) * 6;

    // ---- xt load ----
    const float* xb = x + (size_t)b * CIN * LPIX;
    for (int i = tid; i < 64 * 5 * 8; i += 1024) {
        const int c  = i / 40;
        const int rm = i - c * 40;
        const int hi = h0 - 1 + (rm >> 3);
        const int wi = w0 - 1 + (rm & 7);
        float v = 0.0f;
        if (hi >= 0 && hi < HH && wi >= 0 && wi < WW)
            v = xb[c * LPIX + hi * WW + wi];
        xt[i] = v;
    }
    __syncthreads();

    // ---- pred B-frags from center x (t-independent) ----
    short8v Bf[4][2];
    #pragma unroll
    for (int g = 0; g < 4; ++g) {
        #pragma unroll
        for (int nt = 0; nt < 2; ++nt) {
            const int px = nt * 16 + lrow;
            short8v f = (short8v)0;
            if (quad < 2 && px < NPX) {
                const int pr = px / 6, pc = px - 6 * (px / 6);
                #pragma unroll
                for (int j = 0; j < 8; ++j)
                    f[j] = (short)f2bf(xt[((g * 16 + quad * 8 + j) * 5 + pr + 1) * 8 + pc + 1]);
            }
            if (quad == 2 && px < NPX) f[0] = (short)0x3F80;   // bf16(1.0) bias slot
            Bf[g][nt] = f;
        }
    }

    // ---- Q + dyn_b phase (group 3), Q -> Qs as [px][o*18+d] ----
    for (int u = wave; u < 68; u += 16) {
        const int ch0  = WSZ + u * 16;
        const int mych = ch0 + lrow;
        short8v a = (short8v)0;
        if (quad < 2)       a = *(const short8v*)(Wb + (size_t)mych * 16 + quad * 8);
        else if (quad == 2) a[0] = (short)f2bf(bp[mych]);
        #pragma unroll
        for (int nt = 0; nt < 2; ++nt) {
            float4v Dv = {0.f, 0.f, 0.f, 0.f};
            Dv = __builtin_amdgcn_mfma_f32_16x16x32_bf16(a, Bf[3][nt], Dv, 0, 0, 0);
            const int px = nt * 16 + lrow;
            if (px < NPX) {
                #pragma unroll
                for (int rr = 0; rr < 4; ++rr) {
                    const int ch = ch0 + quad * 4 + rr;
                    if (ch < WSZ + PSZ) {
                        const int i = ch - WSZ;
                        Qs[px * QS2 + (i >> 4) * 18 + (i & 15)] = f2bf(Dv[rr]);
                    } else {
                        dynb[px * DBS + (ch - WSZ - PSZ)] = Dv[rr];
                    }
                }
            }
        }
    }

    // ---- pred slice for tap t into buf (STATIC Bf indices via literal PASS) ----
    #define PASS(GG, NT)                                                              \
        { short8v am = (myg == (GG)) ? a : (short8v)0;                                \
          Dv = __builtin_amdgcn_mfma_f32_16x16x32_bf16(am, Bf[GG][NT], Dv, 0, 0, 0); }

    #define PRED_SLICE(T, BUF)                                                        \
    for (int u = wave; u < 64; u += 16) {                                             \
        const int d  = u >> 2;                                                        \
        const int c0 = (u & 3) * 16;                                                  \
        const int ch0  = d * 576 + c0 * 9 + (T);                                      \
        const int mych = ch0 + 9 * lrow;                                              \
        short8v a = (short8v)0;                                                       \
        if (quad < 2)       a = *(const short8v*)(Wb + (size_t)mych * 16 + quad * 8); \
        else if (quad == 2) a[0] = (short)f2bf(bp[mych]);                             \
        const int g0  = ch0 / GRPSZ;                                                  \
        const int g1  = (ch0 + 135) / GRPSZ;                                          \
        const int myg = mych / GRPSZ;                                                 \
        _Pragma("unroll")                                                             \
        for (int nt = 0; nt < 2; ++nt) {                                              \
            float4v Dv = {0.f, 0.f, 0.f, 0.f};                                        \
            if (g0 == 0)      { PASS(0, nt) if (g1 == 1) PASS(1, nt) }                \
            else if (g0 == 1) { PASS(1, nt) if (g1 == 2) PASS(2, nt) }                \
            else if (g0 == 2) { PASS(2, nt) if (g1 == 3) PASS(3, nt) }                \
            else              { PASS(3, nt) }                                         \
            const int px = nt * 16 + lrow;                                            \
            if (px < NPX) {                                                           \
                _Pragma("unroll")                                                     \
                for (int rr = 0; rr < 4; ++rr)                                        \
                    S[BUF][px * PXS2 + (c0 + quad * 4 + rr) * 18 + d] = f2bf(Dv[rr]); \
            }                                                                         \
        }                                                                             \
    }

    PRED_SLICE(0, 0)
    __syncthreads();   // covers Qs, dynb, S[0]

    // ---- Y-task assignment: 72 (px,Nt) tasks over 16 waves ----
    const int ntask  = (wave < 8) ? 5 : 4;
    const int tstart = (wave < 8) ? 5 * wave : 40 + 4 * (wave - 8);
    float acc[5] = {0.f, 0.f, 0.f, 0.f, 0.f};

    for (int t = 0; t < KK; ++t) {
        const int buf = t & 1;
        if (t < 8) { PRED_SLICE(t + 1, (t + 1) & 1) }

        const int tr = t / 3, tc = t - 3 * (t / 3);

        int lastpx = -1;
        short8v Ap[4];
        float pv[4][4];
        #pragma unroll
        for (int k = 0; k < 5; ++k) {
            if (k < ntask) {
                const int tau = tstart + k;
                const int px  = tau >> 2;
                const int Nt  = tau & 3;
                const int pr = px / 6, pc = px - 6 * (px / 6);

                if (px != lastpx) {          // wave-uniform branch
                    lastpx = px;
                    #pragma unroll
                    for (int Mt = 0; Mt < 4; ++Mt) {
                        short8v f = (short8v)0;
                        if (quad < 2)
                            f = *(const short8v*)&S[buf][px * PXS2 + (Mt * 16 + lrow) * 18 + quad * 8];
                        Ap[Mt] = f;
                    }
                    #pragma unroll
                    for (int Mt = 0; Mt < 4; ++Mt)
                        #pragma unroll
                        for (int rr = 0; rr < 4; ++rr) {
                            const int c = Mt * 16 + quad * 4 + rr;
                            pv[Mt][rr] = xt[(c * 5 + pr + tr) * 8 + pc + tc];
                        }
                }

                short8v Bqf = (short8v)0;
                if (quad < 2)
                    Bqf = *(const short8v*)&Qs[px * QS2 + (Nt * 16 + lrow) * 18 + quad * 8];

                float nacc = 0.f, dpacc = 0.f;
                #pragma unroll
                for (int Mt = 0; Mt < 4; ++Mt) {
                    float4v Dv = {0.f, 0.f, 0.f, 0.f};
                    Dv = __builtin_amdgcn_mfma_f32_16x16x32_bf16(Ap[Mt], Bqf, Dv, 0, 0, 0);
                    #pragma unroll
                    for (int rr = 0; rr < 4; ++rr) {
                        nacc  += Dv[rr] * Dv[rr];
                        dpacc += pv[Mt][rr] * Dv[rr];
                    }
                }
                nacc  += __shfl_xor(nacc, 16);  nacc  += __shfl_xor(nacc, 32);
                dpacc += __shfl_xor(dpacc, 16); dpacc += __shfl_xor(dpacc, 32);
                acc[k] += dpacc / fmaxf(sqrtf(fmaxf(nacc, 0.f)), 1e-12f);
            }
        }
        __syncthreads();
    }

    // ---- write out ----
    if (quad == 0) {
        #pragma unroll
        for (int k = 0; k < 5; ++k) {
            if (k < ntask) {
                const int tau = tstart + k;
                const int px  = tau >> 2;
                const int Nt  = tau & 3;
                const int pr = px / 6, pc = px - 6 * (px / 6);
                const int l  = (h0 + pr) * WW + (w0 + pc);
                const int o  = Nt * 16 + lrow;
                out[((size_t)b * OUTC + o) * LPIX + l] = acc[k] + dynb[px * DBS + o];
            }
        }
    }
}

extern "C" void kernel_launch(void* const* d_in, const int* in_sizes, int n_in,
                              void* d_out, int out_size, void* d_ws, size_t ws_size,
                              hipStream_t stream) {
    const float* x  = (const float*)d_in[0];
    const float* Wp = (const float*)d_in[1];
    const float* bp = (const float*)d_in[2];
    float* out = (float*)d_out;
    unsigned short* Wb = (unsigned short*)d_ws;   // PREDCH*16 bf16 = 330 KB
    (void)in_sizes; (void)n_in; (void)out_size; (void)ws_size;

    hipLaunchKernelGGL(cvt_wp, dim3(160), dim3(256), 0, stream, Wp, Wb);
    hipLaunchKernelGGL(dppc10, dim3(BATCH * 128), dim3(1024), 0, stream, x, Wb, bp, out);
}

// Round 4
// 135.543 us; speedup vs baseline: 1.4904x; 1.0051x over previous
//
#include <hip/hip_runtime.h>
#include <math.h>

#define CIN    64
#define OUTC   64
#define BOT    16
#define KK     9
#define HH     48
#define WW     48
#define LPIX   (HH*WW)
#define WSZ    9216
#define PSZ    1024
#define PREDCH 10304
#define GRPSZ  2576
#define BATCH  2
#define NPX    18          // 3 rows x 6 cols of pixels per block
#define PXS2   1172        // px-stride (ushorts): 64*18 + 20 pad (conflict-free)
#define QS2    1160        // Q px-stride (ushorts): 64*18 + 8 pad
#define DBS    65

typedef __attribute__((ext_vector_type(8))) short short8v;
typedef __attribute__((ext_vector_type(4))) float float4v;

__device__ inline unsigned short f2bf(float f){
    unsigned u = __float_as_uint(f);
    return (unsigned short)((u + 0x7FFFu + ((u>>16)&1u)) >> 16);   // RNE
}

__global__ __launch_bounds__(256) void cvt_wp(const float* __restrict__ Wp,
                                              unsigned short* __restrict__ Wb) {
    const int n = PREDCH * 16;
    for (int i = blockIdx.x * 256 + threadIdx.x; i < n; i += gridDim.x * 256)
        Wb[i] = f2bf(Wp[i]);
}

// Block = 18 px (3x6), grid 256 (1/CU), 1024 threads (16 waves).
// vs dppc10 (R3): launch_bounds gains min-waves=4.  R3's default allocation
// targeted 8 waves/EU -> 64 VGPRs -> ~30 MB scratch spills (WRITE_SIZE
// 29.9 MB vs 1.15 MB output), because the allocator can't see that LDS
// (141 KB) already pins us to 1 block = 4 waves/EU.  (1024,4) raises the
// VGPR budget to 128; live state (~100) fits, spills vanish, occupancy
// unchanged (LDS-pinned).
__global__ __launch_bounds__(1024, 4) void dppc11(
    const float* __restrict__ x,
    const unsigned short* __restrict__ Wb,
    const float* __restrict__ bp,
    float* __restrict__ out)
{
    __shared__ float          xt[64 * 5 * 8];       // 10240 B  [c][r5][c8]
    __shared__ unsigned short S[2][NPX * PXS2];     // 84384 B  P_t dbuf
    __shared__ unsigned short Qs[NPX * QS2];        // 41760 B  Q [px][o*18+d]
    __shared__ float          dynb[NPX * DBS];      //  4680 B

    const int tid  = threadIdx.x;
    const int wave = tid >> 6;
    const int lane = tid & 63;
    const int quad = lane >> 4;
    const int lrow = lane & 15;

    const int bi = blockIdx.x;
    const int b  = bi >> 7;
    const int r  = bi & 127;
    const int h0 = (r >> 3) * 3;
    const int w0 = (r & 7) * 6;

    // ---- xt load ----
    const float* xb = x + (size_t)b * CIN * LPIX;
    for (int i = tid; i < 64 * 5 * 8; i += 1024) {
        const int c  = i / 40;
        const int rm = i - c * 40;
        const int hi = h0 - 1 + (rm >> 3);
        const int wi = w0 - 1 + (rm & 7);
        float v = 0.0f;
        if (hi >= 0 && hi < HH && wi >= 0 && wi < WW)
            v = xb[c * LPIX + hi * WW + wi];
        xt[i] = v;
    }
    __syncthreads();

    // ---- pred B-frags from center x (t-independent) ----
    short8v Bf[4][2];
    #pragma unroll
    for (int g = 0; g < 4; ++g) {
        #pragma unroll
        for (int nt = 0; nt < 2; ++nt) {
            const int px = nt * 16 + lrow;
            short8v f = (short8v)0;
            if (quad < 2 && px < NPX) {
                const int pr = px / 6, pc = px - 6 * (px / 6);
                #pragma unroll
                for (int j = 0; j < 8; ++j)
                    f[j] = (short)f2bf(xt[((g * 16 + quad * 8 + j) * 5 + pr + 1) * 8 + pc + 1]);
            }
            if (quad == 2 && px < NPX) f[0] = (short)0x3F80;   // bf16(1.0) bias slot
            Bf[g][nt] = f;
        }
    }

    // ---- Q + dyn_b phase (group 3), Q -> Qs as [px][o*18+d] ----
    for (int u = wave; u < 68; u += 16) {
        const int ch0  = WSZ + u * 16;
        const int mych = ch0 + lrow;
        short8v a = (short8v)0;
        if (quad < 2)       a = *(const short8v*)(Wb + (size_t)mych * 16 + quad * 8);
        else if (quad == 2) a[0] = (short)f2bf(bp[mych]);
        #pragma unroll
        for (int nt = 0; nt < 2; ++nt) {
            float4v Dv = {0.f, 0.f, 0.f, 0.f};
            Dv = __builtin_amdgcn_mfma_f32_16x16x32_bf16(a, Bf[3][nt], Dv, 0, 0, 0);
            const int px = nt * 16 + lrow;
            if (px < NPX) {
                #pragma unroll
                for (int rr = 0; rr < 4; ++rr) {
                    const int ch = ch0 + quad * 4 + rr;
                    if (ch < WSZ + PSZ) {
                        const int i = ch - WSZ;
                        Qs[px * QS2 + (i >> 4) * 18 + (i & 15)] = f2bf(Dv[rr]);
                    } else {
                        dynb[px * DBS + (ch - WSZ - PSZ)] = Dv[rr];
                    }
                }
            }
        }
    }

    // ---- pred slice for tap t into buf (STATIC Bf indices via literal PASS) ----
    #define PASS(GG, NT)                                                              \
        { short8v am = (myg == (GG)) ? a : (short8v)0;                                \
          Dv = __builtin_amdgcn_mfma_f32_16x16x32_bf16(am, Bf[GG][NT], Dv, 0, 0, 0); }

    #define PRED_SLICE(T, BUF)                                                        \
    for (int u = wave; u < 64; u += 16) {                                             \
        const int d  = u >> 2;                                                        \
        const int c0 = (u & 3) * 16;                                                  \
        const int ch0  = d * 576 + c0 * 9 + (T);                                      \
        const int mych = ch0 + 9 * lrow;                                              \
        short8v a = (short8v)0;                                                       \
        if (quad < 2)       a = *(const short8v*)(Wb + (size_t)mych * 16 + quad * 8); \
        else if (quad == 2) a[0] = (short)f2bf(bp[mych]);                             \
        const int g0  = ch0 / GRPSZ;                                                  \
        const int g1  = (ch0 + 135) / GRPSZ;                                          \
        const int myg = mych / GRPSZ;                                                 \
        _Pragma("unroll")                                                             \
        for (int nt = 0; nt < 2; ++nt) {                                              \
            float4v Dv = {0.f, 0.f, 0.f, 0.f};                                        \
            if (g0 == 0)      { PASS(0, nt) if (g1 == 1) PASS(1, nt) }                \
            else if (g0 == 1) { PASS(1, nt) if (g1 == 2) PASS(2, nt) }                \
            else if (g0 == 2) { PASS(2, nt) if (g1 == 3) PASS(3, nt) }                \
            else              { PASS(3, nt) }                                         \
            const int px = nt * 16 + lrow;                                            \
            if (px < NPX) {                                                           \
                _Pragma("unroll")                                                     \
                for (int rr = 0; rr < 4; ++rr)                                        \
                    S[BUF][px * PXS2 + (c0 + quad * 4 + rr) * 18 + d] = f2bf(Dv[rr]); \
            }                                                                         \
        }                                                                             \
    }

    PRED_SLICE(0, 0)
    __syncthreads();   // covers Qs, dynb, S[0]

    // ---- Y-task assignment: 72 (px,Nt) tasks over 16 waves ----
    const int ntask  = (wave < 8) ? 5 : 4;
    const int tstart = (wave < 8) ? 5 * wave : 40 + 4 * (wave - 8);
    float acc[5] = {0.f, 0.f, 0.f, 0.f, 0.f};

    for (int t = 0; t < KK; ++t) {
        const int buf = t & 1;
        if (t < 8) { PRED_SLICE(t + 1, (t + 1) & 1) }

        const int tr = t / 3, tc = t - 3 * (t / 3);

        int lastpx = -1;
        short8v Ap[4];
        float pv[4][4];
        #pragma unroll
        for (int k = 0; k < 5; ++k) {
            if (k < ntask) {
                const int tau = tstart + k;
                const int px  = tau >> 2;
                const int Nt  = tau & 3;
                const int pr = px / 6, pc = px - 6 * (px / 6);

                if (px != lastpx) {          // wave-uniform branch
                    lastpx = px;
                    #pragma unroll
                    for (int Mt = 0; Mt < 4; ++Mt) {
                        short8v f = (short8v)0;
                        if (quad < 2)
                            f = *(const short8v*)&S[buf][px * PXS2 + (Mt * 16 + lrow) * 18 + quad * 8];
                        Ap[Mt] = f;
                    }
                    #pragma unroll
                    for (int Mt = 0; Mt < 4; ++Mt)
                        #pragma unroll
                        for (int rr = 0; rr < 4; ++rr) {
                            const int c = Mt * 16 + quad * 4 + rr;
                            pv[Mt][rr] = xt[(c * 5 + pr + tr) * 8 + pc + tc];
                        }
                }

                short8v Bqf = (short8v)0;
                if (quad < 2)
                    Bqf = *(const short8v*)&Qs[px * QS2 + (Nt * 16 + lrow) * 18 + quad * 8];

                float nacc = 0.f, dpacc = 0.f;
                #pragma unroll
                for (int Mt = 0; Mt < 4; ++Mt) {
                    float4v Dv = {0.f, 0.f, 0.f, 0.f};
                    Dv = __builtin_amdgcn_mfma_f32_16x16x32_bf16(Ap[Mt], Bqf, Dv, 0, 0, 0);
                    #pragma unroll
                    for (int rr = 0; rr < 4; ++rr) {
                        nacc  += Dv[rr] * Dv[rr];
                        dpacc += pv[Mt][rr] * Dv[rr];
                    }
                }
                nacc  += __shfl_xor(nacc, 16);  nacc  += __shfl_xor(nacc, 32);
                dpacc += __shfl_xor(dpacc, 16); dpacc += __shfl_xor(dpacc, 32);
                acc[k] += dpacc / fmaxf(sqrtf(fmaxf(nacc, 0.f)), 1e-12f);
            }
        }
        __syncthreads();
    }

    // ---- write out ----
    if (quad == 0) {
        #pragma unroll
        for (int k = 0; k < 5; ++k) {
            if (k < ntask) {
                const int tau = tstart + k;
                const int px  = tau >> 2;
                const int Nt  = tau & 3;
                const int pr = px / 6, pc = px - 6 * (px / 6);
                const int l  = (h0 + pr) * WW + (w0 + pc);
                const int o  = Nt * 16 + lrow;
                out[((size_t)b * OUTC + o) * LPIX + l] = acc[k] + dynb[px * DBS + o];
            }
        }
    }
}

extern "C" void kernel_launch(void* const* d_in, const int* in_sizes, int n_in,
                              void* d_out, int out_size, void* d_ws, size_t ws_size,
                              hipStream_t stream) {
    const float* x  = (const float*)d_in[0];
    const float* Wp = (const float*)d_in[1];
    const float* bp = (const float*)d_in[2];
    float* out = (float*)d_out;
    unsigned short* Wb = (unsigned short*)d_ws;   // PREDCH*16 bf16 = 330 KB
    (void)in_sizes; (void)n_in; (void)out_size; (void)ws_size;

    hipLaunchKernelGGL(cvt_wp, dim3(160), dim3(256), 0, stream, Wp, Wb);
    hipLaunchKernelGGL(dppc11, dim3(BATCH * 128), dim3(1024), 0, stream, x, Wb, bp, out);
}

// Round 5
// 130.727 us; speedup vs baseline: 1.5453x; 1.0368x over previous
//
#include <hip/hip_runtime.h>
#include <math.h>

#define CIN    64
#define OUTC   64
#define BOT    16
#define KK     9
#define HH     48
#define WW     48
#define LPIX   (HH*WW)
#define WSZ    9216
#define PSZ    1024
#define PREDCH 10304
#define GRPSZ  2576
#define BATCH  2
#define NPX    18          // 3 rows x 6 cols of pixels per block
#define PXS2   1172        // px-stride (ushorts): 64*18 + 20 pad (conflict-free)
#define QS2    1160        // Q px-stride (ushorts): 64*18 + 8 pad
#define DBS    65

typedef __attribute__((ext_vector_type(8))) short short8v;
typedef __attribute__((ext_vector_type(4))) float float4v;

__device__ inline unsigned short f2bf(float f){
    unsigned u = __float_as_uint(f);
    return (unsigned short)((u + 0x7FFFu + ((u>>16)&1u)) >> 16);   // RNE
}

__global__ __launch_bounds__(256) void cvt_wp(const float* __restrict__ Wp,
                                              unsigned short* __restrict__ Wb) {
    const int n = PREDCH * 16;
    for (int i = blockIdx.x * 256 + threadIdx.x; i < n; i += gridDim.x * 256)
        Wb[i] = f2bf(Wp[i]);
}

// Block = 18 px (3x6), grid 256 (1/CU), 1024 threads (16 waves).
// vs dppc11 (R4): launch_bounds(1024,4) was a NO-OP (counters identical to
// R3: VGPR 64, 30 MB scratch).  The min-waves arg only raises the allowed
// budget; the RA heuristic still targets 8 waves/EU -> 64 VGPRs -> spill.
// Fix from both ends:
//  (a) amdgpu_waves_per_eu(4,4) pins max waves/EU = 4 (LDS already pins us
//      there), so the RA budget/heuristic aligns at 128 VGPRs.
//  (b) Bf[4][2] (32 VGPRs live all-kernel, and WAVE-INVARIANT) moves to LDS
//      Bfs (8 KB, total 149.3 KB).  Waves 0-7 build it once (was: all 16
//      waves redundantly); PASS/Q read it as contiguous ds_read_b128.
//      Peak live state drops to ~70 regs.
__global__ __launch_bounds__(1024) __attribute__((amdgpu_waves_per_eu(4, 4)))
void dppc12(
    const float* __restrict__ x,
    const unsigned short* __restrict__ Wb,
    const float* __restrict__ bp,
    float* __restrict__ out)
{
    __shared__ float          xt[64 * 5 * 8];       // 10240 B  [c][r5][c8]
    __shared__ unsigned short S[2][NPX * PXS2];     // 84384 B  P_t dbuf
    __shared__ unsigned short Qs[NPX * QS2];        // 41760 B  Q [px][o*18+d]
    __shared__ unsigned short Bfs[4 * 2 * 64 * 8];  //  8192 B  pred B-frags [g][nt][lane]
    __shared__ float          dynb[NPX * DBS];      //  4680 B

    const int tid  = threadIdx.x;
    const int wave = tid >> 6;
    const int lane = tid & 63;
    const int quad = lane >> 4;
    const int lrow = lane & 15;

    const int bi = blockIdx.x;
    const int b  = bi >> 7;
    const int r  = bi & 127;
    const int h0 = (r >> 3) * 3;
    const int w0 = (r & 7) * 6;

    // ---- xt load ----
    const float* xb = x + (size_t)b * CIN * LPIX;
    for (int i = tid; i < 64 * 5 * 8; i += 1024) {
        const int c  = i / 40;
        const int rm = i - c * 40;
        const int hi = h0 - 1 + (rm >> 3);
        const int wi = w0 - 1 + (rm & 7);
        float v = 0.0f;
        if (hi >= 0 && hi < HH && wi >= 0 && wi < WW)
            v = xb[c * LPIX + hi * WW + wi];
        xt[i] = v;
    }
    __syncthreads();

    // ---- pred B-frags -> LDS (wave-invariant; waves 0-7 build one (g,nt) each) ----
    if (wave < 8) {
        const int g  = wave >> 1;
        const int nt = wave & 1;
        const int px = nt * 16 + lrow;
        short8v f = (short8v)0;
        if (quad < 2 && px < NPX) {
            const int pr = px / 6, pc = px - 6 * (px / 6);
            #pragma unroll
            for (int j = 0; j < 8; ++j)
                f[j] = (short)f2bf(xt[((g * 16 + quad * 8 + j) * 5 + pr + 1) * 8 + pc + 1]);
        }
        if (quad == 2 && px < NPX) f[0] = (short)0x3F80;   // bf16(1.0) bias slot
        *(short8v*)&Bfs[((g * 2 + nt) * 64 + lane) * 8] = f;
    }
    __syncthreads();

    // ---- Q + dyn_b phase (group 3), Q -> Qs as [px][o*18+d] ----
    for (int u = wave; u < 68; u += 16) {
        const int ch0  = WSZ + u * 16;
        const int mych = ch0 + lrow;
        short8v a = (short8v)0;
        if (quad < 2)       a = *(const short8v*)(Wb + (size_t)mych * 16 + quad * 8);
        else if (quad == 2) a[0] = (short)f2bf(bp[mych]);
        #pragma unroll
        for (int nt = 0; nt < 2; ++nt) {
            const short8v bfr = *(const short8v*)&Bfs[((3 * 2 + nt) * 64 + lane) * 8];
            float4v Dv = {0.f, 0.f, 0.f, 0.f};
            Dv = __builtin_amdgcn_mfma_f32_16x16x32_bf16(a, bfr, Dv, 0, 0, 0);
            const int px = nt * 16 + lrow;
            if (px < NPX) {
                #pragma unroll
                for (int rr = 0; rr < 4; ++rr) {
                    const int ch = ch0 + quad * 4 + rr;
                    if (ch < WSZ + PSZ) {
                        const int i = ch - WSZ;
                        Qs[px * QS2 + (i >> 4) * 18 + (i & 15)] = f2bf(Dv[rr]);
                    } else {
                        dynb[px * DBS + (ch - WSZ - PSZ)] = Dv[rr];
                    }
                }
            }
        }
    }

    // ---- pred slice for tap t into buf (B-frags from LDS, STATIC g idx) ----
    #define PASS(GG, NT)                                                              \
        { short8v am = (myg == (GG)) ? a : (short8v)0;                                \
          const short8v bfr = *(const short8v*)&Bfs[(((GG) * 2 + (NT)) * 64 + lane) * 8]; \
          Dv = __builtin_amdgcn_mfma_f32_16x16x32_bf16(am, bfr, Dv, 0, 0, 0); }

    #define PRED_SLICE(T, BUF)                                                        \
    for (int u = wave; u < 64; u += 16) {                                             \
        const int d  = u >> 2;                                                        \
        const int c0 = (u & 3) * 16;                                                  \
        const int ch0  = d * 576 + c0 * 9 + (T);                                      \
        const int mych = ch0 + 9 * lrow;                                              \
        short8v a = (short8v)0;                                                       \
        if (quad < 2)       a = *(const short8v*)(Wb + (size_t)mych * 16 + quad * 8); \
        else if (quad == 2) a[0] = (short)f2bf(bp[mych]);                             \
        const int g0  = ch0 / GRPSZ;                                                  \
        const int g1  = (ch0 + 135) / GRPSZ;                                          \
        const int myg = mych / GRPSZ;                                                 \
        _Pragma("unroll")                                                             \
        for (int nt = 0; nt < 2; ++nt) {                                              \
            float4v Dv = {0.f, 0.f, 0.f, 0.f};                                        \
            if (g0 == 0)      { PASS(0, nt) if (g1 == 1) PASS(1, nt) }                \
            else if (g0 == 1) { PASS(1, nt) if (g1 == 2) PASS(2, nt) }                \
            else if (g0 == 2) { PASS(2, nt) if (g1 == 3) PASS(3, nt) }                \
            else              { PASS(3, nt) }                                         \
            const int px = nt * 16 + lrow;                                            \
            if (px < NPX) {                                                           \
                _Pragma("unroll")                                                     \
                for (int rr = 0; rr < 4; ++rr)                                        \
                    S[BUF][px * PXS2 + (c0 + quad * 4 + rr) * 18 + d] = f2bf(Dv[rr]); \
            }                                                                         \
        }                                                                             \
    }

    PRED_SLICE(0, 0)
    __syncthreads();   // covers Qs, dynb, S[0]

    // ---- Y-task assignment: 72 (px,Nt) tasks over 16 waves ----
    const int ntask  = (wave < 8) ? 5 : 4;
    const int tstart = (wave < 8) ? 5 * wave : 40 + 4 * (wave - 8);
    float acc[5] = {0.f, 0.f, 0.f, 0.f, 0.f};

    for (int t = 0; t < KK; ++t) {
        const int buf = t & 1;
        if (t < 8) { PRED_SLICE(t + 1, (t + 1) & 1) }

        const int tr = t / 3, tc = t - 3 * (t / 3);

        int lastpx = -1;
        short8v Ap[4];
        float pv[4][4];
        #pragma unroll
        for (int k = 0; k < 5; ++k) {
            if (k < ntask) {
                const int tau = tstart + k;
                const int px  = tau >> 2;
                const int Nt  = tau & 3;
                const int pr = px / 6, pc = px - 6 * (px / 6);

                if (px != lastpx) {          // wave-uniform branch
                    lastpx = px;
                    #pragma unroll
                    for (int Mt = 0; Mt < 4; ++Mt) {
                        short8v f = (short8v)0;
                        if (quad < 2)
                            f = *(const short8v*)&S[buf][px * PXS2 + (Mt * 16 + lrow) * 18 + quad * 8];
                        Ap[Mt] = f;
                    }
                    #pragma unroll
                    for (int Mt = 0; Mt < 4; ++Mt)
                        #pragma unroll
                        for (int rr = 0; rr < 4; ++rr) {
                            const int c = Mt * 16 + quad * 4 + rr;
                            pv[Mt][rr] = xt[(c * 5 + pr + tr) * 8 + pc + tc];
                        }
                }

                short8v Bqf = (short8v)0;
                if (quad < 2)
                    Bqf = *(const short8v*)&Qs[px * QS2 + (Nt * 16 + lrow) * 18 + quad * 8];

                float nacc = 0.f, dpacc = 0.f;
                #pragma unroll
                for (int Mt = 0; Mt < 4; ++Mt) {
                    float4v Dv = {0.f, 0.f, 0.f, 0.f};
                    Dv = __builtin_amdgcn_mfma_f32_16x16x32_bf16(Ap[Mt], Bqf, Dv, 0, 0, 0);
                    #pragma unroll
                    for (int rr = 0; rr < 4; ++rr) {
                        nacc  += Dv[rr] * Dv[rr];
                        dpacc += pv[Mt][rr] * Dv[rr];
                    }
                }
                nacc  += __shfl_xor(nacc, 16);  nacc  += __shfl_xor(nacc, 32);
                dpacc += __shfl_xor(dpacc, 16); dpacc += __shfl_xor(dpacc, 32);
                acc[k] += dpacc / fmaxf(sqrtf(fmaxf(nacc, 0.f)), 1e-12f);
            }
        }
        __syncthreads();
    }

    // ---- write out ----
    if (quad == 0) {
        #pragma unroll
        for (int k = 0; k < 5; ++k) {
            if (k < ntask) {
                const int tau = tstart + k;
                const int px  = tau >> 2;
                const int Nt  = tau & 3;
                const int pr = px / 6, pc = px - 6 * (px / 6);
                const int l  = (h0 + pr) * WW + (w0 + pc);
                const int o  = Nt * 16 + lrow;
                out[((size_t)b * OUTC + o) * LPIX + l] = acc[k] + dynb[px * DBS + o];
            }
        }
    }
}

extern "C" void kernel_launch(void* const* d_in, const int* in_sizes, int n_in,
                              void* d_out, int out_size, void* d_ws, size_t ws_size,
                              hipStream_t stream) {
    const float* x  = (const float*)d_in[0];
    const float* Wp = (const float*)d_in[1];
    const float* bp = (const float*)d_in[2];
    float* out = (float*)d_out;
    unsigned short* Wb = (unsigned short*)d_ws;   // PREDCH*16 bf16 = 330 KB
    (void)in_sizes; (void)n_in; (void)out_size; (void)ws_size;

    hipLaunchKernelGGL(cvt_wp, dim3(160), dim3(256), 0, stream, Wp, Wb);
    hipLaunchKernelGGL(dppc12, dim3(BATCH * 128), dim3(1024), 0, stream, x, Wb, bp, out);
}

// Round 7
// 125.044 us; speedup vs baseline: 1.6155x; 1.0455x over previous
//
#include <hip/hip_runtime.h>
#include <math.h>

#define CIN    64
#define OUTC   64
#define BOT    16
#define KK     9
#define HH     48
#define WW     48
#define LPIX   (HH*WW)
#define WSZ    9216
#define PSZ    1024
#define PREDCH 10304
#define GRPSZ  2576
#define BATCH  2
#define NPX    18          // 3 rows x 6 cols of pixels per block
#define PXS2   1172        // px-stride (ushorts): 64*18 + 20 pad (conflict-free)
#define QS2    1160        // Q px-stride (ushorts): 64*18 + 8 pad
#define DBS    65

typedef __attribute__((ext_vector_type(8))) short short8v;
typedef __attribute__((ext_vector_type(4))) float float4v;

__device__ inline unsigned short f2bf(float f){
    unsigned u = __float_as_uint(f);
    return (unsigned short)((u + 0x7FFFu + ((u>>16)&1u)) >> 16);   // RNE
}

__global__ __launch_bounds__(256) void cvt_wp(const float* __restrict__ Wp,
                                              unsigned short* __restrict__ Wb) {
    const int n = PREDCH * 16;
    for (int i = blockIdx.x * 256 + threadIdx.x; i < n; i += gridDim.x * 256)
        Wb[i] = f2bf(Wp[i]);
}

// Block = 18 px (3x6), grid 256 (1/CU), 1024 threads (16 waves).
// vs dppc13 (R6, FAILED NaN): R6 bundled {PRED row-remap, cvt_pk asm, packed
// b32 LDS stores, xtT}.  Bisect: this kernel = R5 (passing) + ONLY
//  (b) xtT [spatial][c] transposed copy (10 KB; LDS 159.7 KB): Y-phase pv
//      gather = 4x broadcast ds_read_b128 (was 16x ds_read_b32 + ~48 addr
//      VALU per px-change).  Filled by waves 8-15 concurrent with Bfs build.
//  (c') Q-phase packed b32 stores in PURE C (f2bf|f2bf<<16, no asm) - the
//      Q store indices were already d-consecutive; bounded probe of the
//      uint-through-ushort LDS store mechanism (Q runs once vs PRED x9).
// PRED_SLICE reverts to R5 verbatim (old row mapping, scalar b16 stores).
__global__ __launch_bounds__(1024) __attribute__((amdgpu_waves_per_eu(4, 4)))
void dppc14(
    const float* __restrict__ x,
    const unsigned short* __restrict__ Wb,
    const float* __restrict__ bp,
    float* __restrict__ out)
{
    __shared__ float          xt[64 * 5 * 8];       // 10240 B  [c][r5][c8]
    __shared__ float          xtT[5 * 8 * 64];      // 10240 B  [r5*8+c8][c]
    __shared__ unsigned short S[2][NPX * PXS2];     // 84384 B  P_t dbuf
    __shared__ unsigned short Qs[NPX * QS2];        // 41760 B  Q [px][o*18+d]
    __shared__ unsigned short Bfs[4 * 2 * 64 * 8];  //  8192 B  pred B-frags [g][nt][lane]
    __shared__ float          dynb[NPX * DBS];      //  4680 B

    const int tid  = threadIdx.x;
    const int wave = tid >> 6;
    const int lane = tid & 63;
    const int quad = lane >> 4;
    const int lrow = lane & 15;

    const int bi = blockIdx.x;
    const int b  = bi >> 7;
    const int r  = bi & 127;
    const int h0 = (r >> 3) * 3;
    const int w0 = (r & 7) * 6;

    // ---- xt load (coalesced global) ----
    const float* xb = x + (size_t)b * CIN * LPIX;
    for (int i = tid; i < 64 * 5 * 8; i += 1024) {
        const int c  = i / 40;
        const int rm = i - c * 40;
        const int hi = h0 - 1 + (rm >> 3);
        const int wi = w0 - 1 + (rm & 7);
        float v = 0.0f;
        if (hi >= 0 && hi < HH && wi >= 0 && wi < WW)
            v = xb[c * LPIX + hi * WW + wi];
        xt[i] = v;
    }
    __syncthreads();

    // ---- waves 0-7: pred B-frags -> LDS (wave-invariant, built once) ----
    if (wave < 8) {
        const int g  = wave >> 1;
        const int nt = wave & 1;
        const int px = nt * 16 + lrow;
        short8v f = (short8v)0;
        if (quad < 2 && px < NPX) {
            const int pr = px / 6, pc = px - 6 * (px / 6);
            #pragma unroll
            for (int j = 0; j < 8; ++j)
                f[j] = (short)f2bf(xt[((g * 16 + quad * 8 + j) * 5 + pr + 1) * 8 + pc + 1]);
        }
        if (quad == 2 && px < NPX) f[0] = (short)0x3F80;   // bf16(1.0) bias slot
        *(short8v*)&Bfs[((g * 2 + nt) * 64 + lane) * 8] = f;
    } else {
        // ---- waves 8-15: transpose xt -> xtT[spatial][c] (for pv b128 reads) ----
        for (int i = tid - 512; i < 64 * 5 * 8; i += 512) {
            const int sp = i >> 6;
            const int c  = i & 63;
            xtT[i] = xt[c * 40 + sp];
        }
    }
    __syncthreads();

    // ---- Q + dyn_b phase (group 3), Q -> Qs as [px][o*18+d] ----
    for (int u = wave; u < 68; u += 16) {
        const int ch0  = WSZ + u * 16;
        const int mych = ch0 + lrow;
        short8v a = (short8v)0;
        if (quad < 2)       a = *(const short8v*)(Wb + (size_t)mych * 16 + quad * 8);
        else if (quad == 2) a[0] = (short)f2bf(bp[mych]);
        #pragma unroll
        for (int nt = 0; nt < 2; ++nt) {
            const short8v bfr = *(const short8v*)&Bfs[((3 * 2 + nt) * 64 + lane) * 8];
            float4v Dv = {0.f, 0.f, 0.f, 0.f};
            Dv = __builtin_amdgcn_mfma_f32_16x16x32_bf16(a, bfr, Dv, 0, 0, 0);
            const int px = nt * 16 + lrow;
            if (px < NPX) {
                if (u < 64) {   // proj region: 4 consecutive ushorts, C-packed b32
                    const unsigned r01 = (unsigned)f2bf(Dv[0]) | ((unsigned)f2bf(Dv[1]) << 16);
                    const unsigned r23 = (unsigned)f2bf(Dv[2]) | ((unsigned)f2bf(Dv[3]) << 16);
                    unsigned short* p = &Qs[px * QS2 + u * 18 + quad * 4];
                    *(unsigned int*)(p)     = r01;
                    *(unsigned int*)(p + 2) = r23;
                } else {        // dyn_b region
                    #pragma unroll
                    for (int rr = 0; rr < 4; ++rr)
                        dynb[px * DBS + (u - 64) * 16 + quad * 4 + rr] = Dv[rr];
                }
            }
        }
    }

    // ---- pred slice for tap t into buf (R5-verbatim mapping & stores) ----
    #define PASS(GG, NT)                                                              \
        { short8v am = (myg == (GG)) ? a : (short8v)0;                                \
          const short8v bfr = *(const short8v*)&Bfs[(((GG) * 2 + (NT)) * 64 + lane) * 8]; \
          Dv = __builtin_amdgcn_mfma_f32_16x16x32_bf16(am, bfr, Dv, 0, 0, 0); }

    #define PRED_SLICE(T, BUF)                                                        \
    for (int u = wave; u < 64; u += 16) {                                             \
        const int d  = u >> 2;                                                        \
        const int c0 = (u & 3) * 16;                                                  \
        const int ch0  = d * 576 + c0 * 9 + (T);                                      \
        const int mych = ch0 + 9 * lrow;                                              \
        short8v a = (short8v)0;                                                       \
        if (quad < 2)       a = *(const short8v*)(Wb + (size_t)mych * 16 + quad * 8); \
        else if (quad == 2) a[0] = (short)f2bf(bp[mych]);                             \
        const int g0  = ch0 / GRPSZ;                                                  \
        const int g1  = (ch0 + 135) / GRPSZ;                                          \
        const int myg = mych / GRPSZ;                                                 \
        _Pragma("unroll")                                                             \
        for (int nt = 0; nt < 2; ++nt) {                                              \
            float4v Dv = {0.f, 0.f, 0.f, 0.f};                                        \
            if (g0 == 0)      { PASS(0, nt) if (g1 == 1) PASS(1, nt) }                \
            else if (g0 == 1) { PASS(1, nt) if (g1 == 2) PASS(2, nt) }                \
            else if (g0 == 2) { PASS(2, nt) if (g1 == 3) PASS(3, nt) }                \
            else              { PASS(3, nt) }                                         \
            const int px = nt * 16 + lrow;                                            \
            if (px < NPX) {                                                           \
                _Pragma("unroll")                                                     \
                for (int rr = 0; rr < 4; ++rr)                                        \
                    S[BUF][px * PXS2 + (c0 + quad * 4 + rr) * 18 + d] = f2bf(Dv[rr]); \
            }                                                                         \
        }                                                                             \
    }

    PRED_SLICE(0, 0)
    __syncthreads();   // covers Qs, dynb, S[0]

    // ---- Y-task assignment: 72 (px,Nt) tasks over 16 waves ----
    const int ntask  = (wave < 8) ? 5 : 4;
    const int tstart = (wave < 8) ? 5 * wave : 40 + 4 * (wave - 8);
    float acc[5] = {0.f, 0.f, 0.f, 0.f, 0.f};

    for (int t = 0; t < KK; ++t) {
        const int buf = t & 1;
        if (t < 8) { PRED_SLICE(t + 1, (t + 1) & 1) }

        const int tr = t / 3, tc = t - 3 * (t / 3);

        int lastpx = -1;
        short8v Ap[4];
        float4v pv4[4];
        #pragma unroll
        for (int k = 0; k < 5; ++k) {
            if (k < ntask) {
                const int tau = tstart + k;
                const int px  = tau >> 2;
                const int Nt  = tau & 3;
                const int pr = px / 6, pc = px - 6 * (px / 6);

                if (px != lastpx) {          // wave-uniform branch
                    lastpx = px;
                    #pragma unroll
                    for (int Mt = 0; Mt < 4; ++Mt) {
                        short8v f = (short8v)0;
                        if (quad < 2)
                            f = *(const short8v*)&S[buf][px * PXS2 + (Mt * 16 + lrow) * 18 + quad * 8];
                        Ap[Mt] = f;
                    }
                    const int spb = ((pr + tr) * 8 + pc + tc) * 64;
                    #pragma unroll
                    for (int Mt = 0; Mt < 4; ++Mt)
                        pv4[Mt] = *(const float4v*)&xtT[spb + Mt * 16 + quad * 4];
                }

                short8v Bqf = (short8v)0;
                if (quad < 2)
                    Bqf = *(const short8v*)&Qs[px * QS2 + (Nt * 16 + lrow) * 18 + quad * 8];

                float nacc = 0.f, dpacc = 0.f;
                #pragma unroll
                for (int Mt = 0; Mt < 4; ++Mt) {
                    float4v Dv = {0.f, 0.f, 0.f, 0.f};
                    Dv = __builtin_amdgcn_mfma_f32_16x16x32_bf16(Ap[Mt], Bqf, Dv, 0, 0, 0);
                    #pragma unroll
                    for (int rr = 0; rr < 4; ++rr) {
                        nacc  += Dv[rr] * Dv[rr];
                        dpacc += pv4[Mt][rr] * Dv[rr];
                    }
                }
                nacc  += __shfl_xor(nacc, 16);  nacc  += __shfl_xor(nacc, 32);
                dpacc += __shfl_xor(dpacc, 16); dpacc += __shfl_xor(dpacc, 32);
                acc[k] += dpacc / fmaxf(sqrtf(fmaxf(nacc, 0.f)), 1e-12f);
            }
        }
        __syncthreads();
    }

    // ---- write out ----
    if (quad == 0) {
        #pragma unroll
        for (int k = 0; k < 5; ++k) {
            if (k < ntask) {
                const int tau = tstart + k;
                const int px  = tau >> 2;
                const int Nt  = tau & 3;
                const int pr = px / 6, pc = px - 6 * (px / 6);
                const int l  = (h0 + pr) * WW + (w0 + pc);
                const int o  = Nt * 16 + lrow;
                out[((size_t)b * OUTC + o) * LPIX + l] = acc[k] + dynb[px * DBS + o];
            }
        }
    }
}

extern "C" void kernel_launch(void* const* d_in, const int* in_sizes, int n_in,
                              void* d_out, int out_size, void* d_ws, size_t ws_size,
                              hipStream_t stream) {
    const float* x  = (const float*)d_in[0];
    const float* Wp = (const float*)d_in[1];
    const float* bp = (const float*)d_in[2];
    float* out = (float*)d_out;
    unsigned short* Wb = (unsigned short*)d_ws;   // PREDCH*16 bf16 = 330 KB
    (void)in_sizes; (void)n_in; (void)out_size; (void)ws_size;

    hipLaunchKernelGGL(cvt_wp, dim3(160), dim3(256), 0, stream, Wp, Wb);
    hipLaunchKernelGGL(dppc14, dim3(BATCH * 128), dim3(1024), 0, stream, x, Wb, bp, out);
}